// Round 9
// baseline (471.866 us; speedup 1.0000x reference)
//
#include <hip/hip_runtime.h>
#include <hip/hip_bf16.h>
#include <hip/hip_fp16.h>
#include <cstddef>

#define N_NODES 100000
#define F_IN    512
#define HID     64
#define NCLS    40

#define BUCK_SZ   8
#define NBUCK     (N_NODES / BUCK_SZ)     // 12500, exact
#define SRC_MASK  0x1FFFF                  // 17 bits
#define CUR_PAD   16                       // ints: one cursor per 64B line

// ---------- utility ----------
__global__ void zero_kernel(int* __restrict__ p, int n) {
    int i = blockIdx.x * blockDim.x + threadIdx.x;
    if (i < n) p[i] = 0;
}

// ---------- degree / normalization ----------
__global__ void count_deg_kernel(const int* __restrict__ dst, int* __restrict__ cnt, int E) {
    int e = blockIdx.x * blockDim.x + threadIdx.x;
    if (e < E) atomicAdd(&cnt[dst[e]], 1);
}

__global__ void make_dinv_kernel(const int* __restrict__ cnt, float* __restrict__ dinv, int n) {
    int i = blockIdx.x * blockDim.x + threadIdx.x;
    if (i < n) dinv[i] = rsqrtf((float)(cnt[i] + 1));   // +1 self-loop
}

// ---------- exclusive scan (2-level) over degree counts ----------
#define SCAN_ELEMS 1024

__global__ __launch_bounds__(256) void scan_partial_kernel(const int* __restrict__ cnt,
                                                           int* __restrict__ part, int M) {
    __shared__ int sd[256];
    const int b = blockIdx.x, t = threadIdx.x;
    const int base = b * SCAN_ELEMS;
    int s = 0;
    for (int i = t; i < SCAN_ELEMS; i += 256) {
        int idx = base + i;
        s += (idx < M) ? cnt[idx] : 0;
    }
    sd[t] = s; __syncthreads();
    for (int d = 128; d > 0; d >>= 1) {
        if (t < d) sd[t] += sd[t + d];
        __syncthreads();
    }
    if (t == 0) part[b] = sd[0];
}

__global__ void scan_single_kernel(int* __restrict__ part, int n) {
    __shared__ int sd[128];
    int t = threadIdx.x;
    int v = (t < n) ? part[t] : 0;
    sd[t] = v; __syncthreads();
    for (int d = 1; d < 128; d <<= 1) {
        int u = (t >= d) ? sd[t - d] : 0;
        __syncthreads();
        sd[t] += u;
        __syncthreads();
    }
    if (t < n) part[t] = sd[t] - v;   // exclusive
}

__global__ __launch_bounds__(256) void scan_final_kernel(const int* __restrict__ cnt,
                                                         const int* __restrict__ part,
                                                         int* __restrict__ off, int M) {
    __shared__ int sd[256];
    const int b = blockIdx.x, t = threadIdx.x;
    const int base = b * SCAN_ELEMS + t * 4;
    int cs[4];
    #pragma unroll
    for (int i = 0; i < 4; ++i) cs[i] = (base + i < M) ? cnt[base + i] : 0;
    const int tot = cs[0] + cs[1] + cs[2] + cs[3];
    sd[t] = tot; __syncthreads();
    for (int d = 1; d < 256; d <<= 1) {
        int u = (t >= d) ? sd[t - d] : 0;
        __syncthreads();
        sd[t] += u;
        __syncthreads();
    }
    int run = sd[t] - tot + part[b];
    #pragma unroll
    for (int i = 0; i < 4; ++i) {
        if (base + i < M) off[base + i] = run;
        run += cs[i];
    }
    if (base < M && base + 4 >= M) off[M] = run;
}

// ---------- bucket cursors (padded: one per 64B line) ----------
__global__ void init_bcur_kernel(const int* __restrict__ off, int* __restrict__ bcur, int nb) {
    int i = blockIdx.x * blockDim.x + threadIdx.x;
    if (i < nb) bcur[i * CUR_PAD] = off[i * BUCK_SZ];
}

// ---------- phase 1: scatter edges into coarse dst-buckets ----------
__global__ void scatter_bucket_kernel(const int* __restrict__ src, const int* __restrict__ dst,
                                      int* __restrict__ bcur,
                                      unsigned int* __restrict__ ebuf, int E) {
    int e = blockIdx.x * blockDim.x + threadIdx.x;
    if (e < E) {
        int d = dst[e];
        int s = src[e];
        int b = d / BUCK_SZ;
        int pos = atomicAdd(&bcur[b * CUR_PAD], 1);
        ebuf[pos] = (unsigned int)s | ((unsigned int)(d & (BUCK_SZ - 1)) << 17);
    }
}

// ---------- phase 2: within-bucket counting place -> per-node CSR ----------
__global__ __launch_bounds__(64) void sort_bucket_kernel(const unsigned int* __restrict__ ebuf,
                                                         const int* __restrict__ off,
                                                         int* __restrict__ csr_src, int M) {
    __shared__ int lcur[BUCK_SZ];
    const int b = blockIdx.x, t = threadIdx.x;
    const int base = b * BUCK_SZ;
    if (t < BUCK_SZ) lcur[t] = off[base + t];
    __syncthreads();
    const int e0 = off[base];
    const int e1 = off[base + BUCK_SZ];
    for (int e = e0 + t; e < e1; e += 64) {
        unsigned int pk = ebuf[e];
        int loc = pk >> 17;
        int pos = atomicAdd(&lcur[loc], 1);
        csr_src[pos] = (int)(pk & SRC_MASK);
    }
}

// ---------- GEMM1: H1 = X (Mx512) @ W1 (512x64), fp16 output ----------
#define BK 32
__global__ __launch_bounds__(256) void gemm1_kernel(const float* __restrict__ X,
                                                    const float* __restrict__ W,
                                                    __half* __restrict__ H,
                                                    int M) {
    __shared__ float As[BK][68];
    __shared__ float Bs[BK][64];

    const int tid = threadIdx.x;
    const int tx = tid & 15;
    const int ty = tid >> 4;
    const int rowBase = blockIdx.x * 64;

    const int a_row = tid >> 3;
    const int a_q   = tid & 7;
    const int b_row = tid >> 4;
    const int b_c4  = tid & 15;

    float acc[4][4] = {};

    for (int kt = 0; kt < F_IN; kt += BK) {
        #pragma unroll
        for (int h = 0; h < 2; ++h) {
            int r = a_row + h * 32;
            int gr = rowBase + r;
            if (gr >= M) gr = M - 1;
            const float4 v = *reinterpret_cast<const float4*>(
                &X[(size_t)gr * F_IN + kt + a_q * 4]);
            As[a_q * 4 + 0][r] = v.x;
            As[a_q * 4 + 1][r] = v.y;
            As[a_q * 4 + 2][r] = v.z;
            As[a_q * 4 + 3][r] = v.w;
        }
        #pragma unroll
        for (int h = 0; h < 2; ++h) {
            int kr = b_row + h * 16;
            const float4 v = *reinterpret_cast<const float4*>(
                &W[(size_t)(kt + kr) * 64 + b_c4 * 4]);
            *reinterpret_cast<float4*>(&Bs[kr][b_c4 * 4]) = v;
        }
        __syncthreads();

        #pragma unroll
        for (int k = 0; k < BK; ++k) {
            const float4 a = *reinterpret_cast<const float4*>(&As[k][ty * 4]);
            const float4 b = *reinterpret_cast<const float4*>(&Bs[k][tx * 4]);
            acc[0][0] += a.x * b.x; acc[0][1] += a.x * b.y; acc[0][2] += a.x * b.z; acc[0][3] += a.x * b.w;
            acc[1][0] += a.y * b.x; acc[1][1] += a.y * b.y; acc[1][2] += a.y * b.z; acc[1][3] += a.y * b.w;
            acc[2][0] += a.z * b.x; acc[2][1] += a.z * b.y; acc[2][2] += a.z * b.z; acc[2][3] += a.z * b.w;
            acc[3][0] += a.w * b.x; acc[3][1] += a.w * b.y; acc[3][2] += a.w * b.z; acc[3][3] += a.w * b.w;
        }
        __syncthreads();
    }

    #pragma unroll
    for (int i = 0; i < 4; ++i) {
        int gr = rowBase + ty * 4 + i;
        if (gr < M) {
            __half2 p0 = __floats2half2_rn(acc[i][0], acc[i][1]);
            __half2 p1 = __floats2half2_rn(acc[i][2], acc[i][3]);
            *reinterpret_cast<__half2*>(&H[(size_t)gr * HID + tx * 4])     = p0;
            *reinterpret_cast<__half2*>(&H[(size_t)gr * HID + tx * 4 + 2]) = p1;
        }
    }
}

// ---------- agg pass 1: z = relu(A*h + b1), DUAL-EDGE half2 gather ----------
// wave = one node; lanes 0-31 process even edges, 32-63 odd edges; each lane
// covers 2 columns (half2). Cross-half combine via shfl_xor(32).
__global__ __launch_bounds__(256) void agg_relu_kernel(const __half* __restrict__ h,
                                                       const int* __restrict__ off,
                                                       const int* __restrict__ csr_src,
                                                       const float* __restrict__ dinv,
                                                       const float* __restrict__ b1,
                                                       __half* __restrict__ z, int M) {
    const int lane = threadIdx.x & 63;
    const int half = lane >> 5;       // 0 = even edges, 1 = odd edges
    const int c    = lane & 31;       // column pair index (cols 2c, 2c+1)
    const int n = blockIdx.x * 4 + (threadIdx.x >> 6);
    if (n >= M) return;

    const float di = dinv[n];
    float2 acc = make_float2(0.f, 0.f);

    const int s0 = off[n], s1 = off[n + 1];
    for (int e = s0; e < s1; ) {
        int   s  = 0;
        float nm = 0.f;
        if (e + lane < s1) {
            s  = csr_src[e + lane];
            nm = dinv[s] * di;
        }
        const int cnt = min(64, s1 - e);
        int j = 0;
        for (; j + 8 <= cnt; j += 8) {
            #pragma unroll
            for (int q = 0; q < 4; ++q) {
                int idx = j + q * 2 + half;
                int   sj = __shfl(s, idx);
                float nj = __shfl(nm, idx);
                __half2 hv = *reinterpret_cast<const __half2*>(&h[(size_t)sj * HID + 2 * c]);
                float2 f = __half22float2(hv);
                acc.x = fmaf(f.x, nj, acc.x);
                acc.y = fmaf(f.y, nj, acc.y);
            }
        }
        for (; j < cnt; j += 2) {
            int idx = j + half;                 // idx==cnt reads nm=0 lane (safe)
            int   sj = __shfl(s, idx);
            float nj = __shfl(nm, idx);
            __half2 hv = *reinterpret_cast<const __half2*>(&h[(size_t)sj * HID + 2 * c]);
            float2 f = __half22float2(hv);
            acc.x = fmaf(f.x, nj, acc.x);
            acc.y = fmaf(f.y, nj, acc.y);
        }
        e += cnt;
    }

    // combine halves
    acc.x += __shfl_xor(acc.x, 32);
    acc.y += __shfl_xor(acc.y, 32);

    if (half == 0) {
        // self-loop + bias + relu, cols 2c, 2c+1
        __half2 hv = *reinterpret_cast<const __half2*>(&h[(size_t)n * HID + 2 * c]);
        float2 f = __half22float2(hv);
        float di2 = di * di;
        const float2 bb = *reinterpret_cast<const float2*>(&b1[2 * c]);
        acc.x = fmaxf(fmaf(f.x, di2, acc.x) + bb.x, 0.f);
        acc.y = fmaxf(fmaf(f.y, di2, acc.y) + bb.y, 0.f);
        *reinterpret_cast<__half2*>(&z[(size_t)n * HID + 2 * c]) = __floats2half2_rn(acc.x, acc.y);
    }
}

// ---------- GEMM2: h2 = z (Mx64, fp16) @ W2 (64x40) -> fp16, no bias ----------
__global__ __launch_bounds__(256) void gemm2_kernel(const __half* __restrict__ z,
                                                    const float* __restrict__ W2,
                                                    __half* __restrict__ h2, int M) {
    __shared__ float W2s[HID * NCLS];   // 10.24 KB
    __shared__ float zs[64 * HID];      // 16 KB

    const int tid = threadIdx.x;
    const int rowBase = blockIdx.x * 64;

    for (int i = tid; i < HID * NCLS; i += 256) W2s[i] = W2[i];

    #pragma unroll
    for (int p = 0; p < 2; ++p) {
        int o = tid * 2 + p;            // 0..511 chunks of 8 halves
        int r = o >> 3, c8 = o & 7;
        int gr = rowBase + r;
        float4 raw = make_float4(0.f, 0.f, 0.f, 0.f);
        if (gr < M) raw = *reinterpret_cast<const float4*>(&z[(size_t)gr * HID + c8 * 8]);
        const __half2* hp = reinterpret_cast<const __half2*>(&raw);
        #pragma unroll
        for (int q = 0; q < 4; ++q) {
            float2 f = __half22float2(hp[q]);
            zs[r * HID + c8 * 8 + q * 2]     = f.x;
            zs[r * HID + c8 * 8 + q * 2 + 1] = f.y;
        }
    }
    __syncthreads();

    #pragma unroll
    for (int p = 0; p < 10; ++p) {
        int o = p * 256 + tid;          // 0..2559 = 64 rows x 40 cols
        int r = o / NCLS, j = o - r * NCLS;
        float s = 0.f;
        #pragma unroll
        for (int k = 0; k < HID; ++k) s = fmaf(zs[r * HID + k], W2s[k * NCLS + j], s);
        int gr = rowBase + r;
        if (gr < M) h2[(size_t)gr * NCLS + j] = __float2half(s);
    }
}

// ---------- agg pass 2: out = log_softmax(A*h2 + b2), DUAL-EDGE half2 ----------
__global__ __launch_bounds__(256) void agg2_lsm_kernel(const __half* __restrict__ h2,
                                                       const int* __restrict__ off,
                                                       const int* __restrict__ csr_src,
                                                       const float* __restrict__ dinv,
                                                       const float* __restrict__ b2,
                                                       float* __restrict__ out, int M) {
    const int lane = threadIdx.x & 63;
    const int half = lane >> 5;
    const int c    = lane & 31;       // column pair index; active c<20
    const int n = blockIdx.x * 4 + (threadIdx.x >> 6);
    if (n >= M) return;

    const bool act = (c < 20);
    const float di = dinv[n];
    float2 acc = make_float2(0.f, 0.f);

    const int s0 = off[n], s1 = off[n + 1];
    for (int e = s0; e < s1; ) {
        int   s  = 0;
        float nm = 0.f;
        if (e + lane < s1) {
            s  = csr_src[e + lane];
            nm = dinv[s] * di;
        }
        const int cnt = min(64, s1 - e);
        int j = 0;
        for (; j + 8 <= cnt; j += 8) {
            #pragma unroll
            for (int q = 0; q < 4; ++q) {
                int idx = j + q * 2 + half;
                int   sj = __shfl(s, idx);
                float nj = __shfl(nm, idx);
                if (act) {
                    __half2 hv = *reinterpret_cast<const __half2*>(&h2[(size_t)sj * NCLS + 2 * c]);
                    float2 f = __half22float2(hv);
                    acc.x = fmaf(f.x, nj, acc.x);
                    acc.y = fmaf(f.y, nj, acc.y);
                }
            }
        }
        for (; j < cnt; j += 2) {
            int idx = j + half;
            int   sj = __shfl(s, idx);
            float nj = __shfl(nm, idx);
            if (act) {
                __half2 hv = *reinterpret_cast<const __half2*>(&h2[(size_t)sj * NCLS + 2 * c]);
                float2 f = __half22float2(hv);
                acc.x = fmaf(f.x, nj, acc.x);
                acc.y = fmaf(f.y, nj, acc.y);
            }
        }
        e += cnt;
    }

    // combine halves
    acc.x += __shfl_xor(acc.x, 32);
    acc.y += __shfl_xor(acc.y, 32);

    // self-loop + bias (lanes 0-31, c<20)
    float lx = -1e30f, ly = -1e30f;
    if (act) {
        __half2 hv = *reinterpret_cast<const __half2*>(&h2[(size_t)n * NCLS + 2 * c]);
        float2 f = __half22float2(hv);
        float di2 = di * di;
        const float2 bb = *reinterpret_cast<const float2*>(&b2[2 * c]);
        lx = fmaf(f.x, di2, acc.x) + bb.x;
        ly = fmaf(f.y, di2, acc.y) + bb.y;
    }

    // log_softmax across lanes 0-31 (each holds 2 logits; c>=20 hold -1e30)
    float m = fmaxf(lx, ly);
    #pragma unroll
    for (int o = 16; o >= 1; o >>= 1) m = fmaxf(m, __shfl_xor(m, o));
    float ex = (act ? __expf(lx - m) + __expf(ly - m) : 0.f);
    float sm = ex;
    #pragma unroll
    for (int o = 16; o >= 1; o >>= 1) sm += __shfl_xor(sm, o);
    float lse = m + __logf(sm);

    if (half == 0 && act) {
        float2 res = make_float2(lx - lse, ly - lse);
        *reinterpret_cast<float2*>(&out[(size_t)n * NCLS + 2 * c]) = res;
    }
}

extern "C" void kernel_launch(void* const* d_in, const int* in_sizes, int n_in,
                              void* d_out, int out_size, void* d_ws, size_t ws_size,
                              hipStream_t stream) {
    const float* x  = (const float*)d_in[0];
    const int*   ei = (const int*)d_in[1];
    const float* W1 = (const float*)d_in[2];
    const float* b1 = (const float*)d_in[3];
    const float* W2 = (const float*)d_in[4];
    const float* b2 = (const float*)d_in[5];
    float* out = (float*)d_out;

    const int M = N_NODES;
    const int E = in_sizes[1] / 2;
    const int* src = ei;
    const int* dst = ei + E;

    // ---- workspace layout (peak ~48.4 MB; ws_size ≈ 800 MB per fill counters) ----
    char* ws = (char*)d_ws;
    int*          cnt     = (int*)         (ws + 0);           // 400 KB
    float*        dinv    = (float*)       (ws + 409600);      // 400 KB
    int*          off     = (int*)         (ws + 819200);      // 400 KB + 4
    int*          part    = (int*)         (ws + 1232896);     // 392 B
    int*          bcur    = (int*)         (ws + 1236992);     // 12500*64 B = 800 KB
    int*          csr_src = (int*)         (ws + 2036992);     // 6.4 MB
    unsigned int* ebuf    = (unsigned int*)(ws + 8436992);     // 6.4 MB
    __half*       h1      = (__half*)      (ws + 14836992);    // 12.8 MB
    __half*       z       = (__half*)      (ws + 27636992);    // 12.8 MB
    __half*       h2      = (__half*)      (ws + 40436992);    // 8 MB -> ends 48,436,992

    const int nPart = (M + SCAN_ELEMS - 1) / SCAN_ELEMS;  // 98

    zero_kernel<<<(M + 255) / 256, 256, 0, stream>>>(cnt, M);
    count_deg_kernel<<<(E + 255) / 256, 256, 0, stream>>>(dst, cnt, E);
    make_dinv_kernel<<<(M + 255) / 256, 256, 0, stream>>>(cnt, dinv, M);

    scan_partial_kernel<<<nPart, 256, 0, stream>>>(cnt, part, M);
    scan_single_kernel<<<1, 128, 0, stream>>>(part, nPart);
    scan_final_kernel<<<nPart, 256, 0, stream>>>(cnt, part, off, M);
    init_bcur_kernel<<<(NBUCK + 255) / 256, 256, 0, stream>>>(off, bcur, NBUCK);

    scatter_bucket_kernel<<<(E + 255) / 256, 256, 0, stream>>>(src, dst, bcur, ebuf, E);
    sort_bucket_kernel<<<NBUCK, 64, 0, stream>>>(ebuf, off, csr_src, M);

    gemm1_kernel<<<(M + 63) / 64, 256, 0, stream>>>(x, W1, h1, M);

    agg_relu_kernel<<<(M + 3) / 4, 256, 0, stream>>>(h1, off, csr_src, dinv, b1, z, M);

    gemm2_kernel<<<(M + 63) / 64, 256, 0, stream>>>(z, W2, h2, M);
    agg2_lsm_kernel<<<(M + 3) / 4, 256, 0, stream>>>(h2, off, csr_src, dinv, b2, out, M);
}

// Round 10
// 413.298 us; speedup vs baseline: 1.1417x; 1.1417x over previous
//
#include <hip/hip_runtime.h>
#include <hip/hip_bf16.h>
#include <hip/hip_fp16.h>
#include <cstddef>

#define N_NODES 100000
#define F_IN    512
#define HID     64
#define NCLS    40

#define BUCK_SZ   8
#define NBUCK     (N_NODES / BUCK_SZ)     // 12500, exact
#define SRC_MASK  0x1FFFF                  // 17 bits
#define CUR_PAD   16                       // ints: one cursor per 64B line

using half8 = __attribute__((ext_vector_type(8))) _Float16;
using f32x4 = __attribute__((ext_vector_type(4))) float;

// ---------- utility ----------
__global__ void zero_kernel(int* __restrict__ p, int n) {
    int i = blockIdx.x * blockDim.x + threadIdx.x;
    if (i < n) p[i] = 0;
}

// ---------- degree ----------
__global__ void count_deg_kernel(const int* __restrict__ dst, int* __restrict__ cnt, int E) {
    int e = blockIdx.x * blockDim.x + threadIdx.x;
    if (e < E) atomicAdd(&cnt[dst[e]], 1);
}

// ---------- exclusive scan (2-level) over degree counts ----------
#define SCAN_ELEMS 1024

__global__ __launch_bounds__(256) void scan_partial_kernel(const int* __restrict__ cnt,
                                                           int* __restrict__ part, int M) {
    __shared__ int sd[256];
    const int b = blockIdx.x, t = threadIdx.x;
    const int base = b * SCAN_ELEMS;
    int s = 0;
    for (int i = t; i < SCAN_ELEMS; i += 256) {
        int idx = base + i;
        s += (idx < M) ? cnt[idx] : 0;
    }
    sd[t] = s; __syncthreads();
    for (int d = 128; d > 0; d >>= 1) {
        if (t < d) sd[t] += sd[t + d];
        __syncthreads();
    }
    if (t == 0) part[b] = sd[0];
}

__global__ void scan_single_kernel(int* __restrict__ part, int n) {
    __shared__ int sd[128];
    int t = threadIdx.x;
    int v = (t < n) ? part[t] : 0;
    sd[t] = v; __syncthreads();
    for (int d = 1; d < 128; d <<= 1) {
        int u = (t >= d) ? sd[t - d] : 0;
        __syncthreads();
        sd[t] += u;
        __syncthreads();
    }
    if (t < n) part[t] = sd[t] - v;   // exclusive
}

// scan_final also emits dinv (reads cnt anyway) and bucket cursors
__global__ __launch_bounds__(256) void scan_final_kernel(const int* __restrict__ cnt,
                                                         const int* __restrict__ part,
                                                         int* __restrict__ off,
                                                         float* __restrict__ dinv,
                                                         int* __restrict__ bcur, int M) {
    __shared__ int sd[256];
    const int b = blockIdx.x, t = threadIdx.x;
    const int base = b * SCAN_ELEMS + t * 4;
    int cs[4];
    #pragma unroll
    for (int i = 0; i < 4; ++i) cs[i] = (base + i < M) ? cnt[base + i] : 0;
    const int tot = cs[0] + cs[1] + cs[2] + cs[3];
    sd[t] = tot; __syncthreads();
    for (int d = 1; d < 256; d <<= 1) {
        int u = (t >= d) ? sd[t - d] : 0;
        __syncthreads();
        sd[t] += u;
        __syncthreads();
    }
    int run = sd[t] - tot + part[b];
    #pragma unroll
    for (int i = 0; i < 4; ++i) {
        int node = base + i;
        if (node < M) {
            off[node] = run;
            dinv[node] = rsqrtf((float)(cs[i] + 1));          // +1 self-loop
            if ((node & (BUCK_SZ - 1)) == 0)
                bcur[(node / BUCK_SZ) * CUR_PAD] = run;       // bucket cursor start
        }
        run += cs[i];
    }
    if (base < M && base + 4 >= M) off[M] = run;
}

// ---------- phase 1: scatter edges into coarse dst-buckets ----------
__global__ void scatter_bucket_kernel(const int* __restrict__ src, const int* __restrict__ dst,
                                      int* __restrict__ bcur,
                                      unsigned int* __restrict__ ebuf, int E) {
    int e = blockIdx.x * blockDim.x + threadIdx.x;
    if (e < E) {
        int d = dst[e];
        int s = src[e];
        int b = d / BUCK_SZ;
        int pos = atomicAdd(&bcur[b * CUR_PAD], 1);
        ebuf[pos] = (unsigned int)s | ((unsigned int)(d & (BUCK_SZ - 1)) << 17);
    }
}

// ---------- phase 2: within-bucket counting place -> per-node CSR ----------
__global__ __launch_bounds__(64) void sort_bucket_kernel(const unsigned int* __restrict__ ebuf,
                                                         const int* __restrict__ off,
                                                         int* __restrict__ csr_src, int M) {
    __shared__ int lcur[BUCK_SZ];
    const int b = blockIdx.x, t = threadIdx.x;
    const int base = b * BUCK_SZ;
    if (t < BUCK_SZ) lcur[t] = off[base + t];
    __syncthreads();
    const int e0 = off[base];
    const int e1 = off[base + BUCK_SZ];
    for (int e = e0 + t; e < e1; e += 64) {
        unsigned int pk = ebuf[e];
        int loc = pk >> 17;
        int pos = atomicAdd(&lcur[loc], 1);
        csr_src[pos] = (int)(pk & SRC_MASK);
    }
}

// ---------- GEMM1 (MFMA fp16): H1 = X (Mx512) @ W1 (512x64), fp16 out ----------
// block: 256 thr = 4 waves; tile 64 rows x 64 cols; BK=32.
// wave w computes rows [w*16, w*16+16) x 64 cols = 4 mfma 16x16 tiles.
// LDS staged in FRAGMENT order: As[kg][row][j] (k = kg*8+j), Bs[kg][col][j].
__global__ __launch_bounds__(256) void gemm1_mfma_kernel(const float* __restrict__ X,
                                                         const float* __restrict__ W,
                                                         __half* __restrict__ H, int M) {
    __shared__ _Float16 As[4][64][8];   // 4 KB
    __shared__ _Float16 Bs[4][64][8];   // 4 KB

    const int tid  = threadIdx.x;
    const int lane = tid & 63;
    const int w    = tid >> 6;
    const int l15  = lane & 15;
    const int kg   = lane >> 4;
    const int rowBase = blockIdx.x * 64;

    f32x4 acc[4] = {};

    for (int kt = 0; kt < F_IN; kt += 32) {
        // stage A tile: 64 rows x 32 k (2048 halves); each thread 2 float4
        #pragma unroll
        for (int p = 0; p < 2; ++p) {
            int idx = tid * 2 + p;           // 0..511
            int r = idx >> 3, k4 = idx & 7;  // row, k-quad (k = k4*4)
            int gr = rowBase + r; if (gr >= M) gr = M - 1;
            const float4 v = *reinterpret_cast<const float4*>(
                &X[(size_t)gr * F_IN + kt + k4 * 4]);
            _Float16* dstp = &As[k4 >> 1][r][(k4 & 1) * 4];
            dstp[0] = (_Float16)v.x; dstp[1] = (_Float16)v.y;
            dstp[2] = (_Float16)v.z; dstp[3] = (_Float16)v.w;
        }
        // stage B tile: 32 k x 64 cols
        #pragma unroll
        for (int p = 0; p < 2; ++p) {
            int idx = tid * 2 + p;           // 0..511
            int k = idx >> 4, c4 = idx & 15; // k-row, col-quad
            const float4 v = *reinterpret_cast<const float4*>(
                &W[(size_t)(kt + k) * HID + c4 * 4]);
            int kgg = k >> 3, j = k & 7;
            Bs[kgg][c4 * 4 + 0][j] = (_Float16)v.x;
            Bs[kgg][c4 * 4 + 1][j] = (_Float16)v.y;
            Bs[kgg][c4 * 4 + 2][j] = (_Float16)v.z;
            Bs[kgg][c4 * 4 + 3][j] = (_Float16)v.w;
        }
        __syncthreads();

        const half8 a = *reinterpret_cast<const half8*>(&As[kg][w * 16 + l15][0]);
        #pragma unroll
        for (int ct = 0; ct < 4; ++ct) {
            const half8 b = *reinterpret_cast<const half8*>(&Bs[kg][ct * 16 + l15][0]);
            acc[ct] = __builtin_amdgcn_mfma_f32_16x16x32_f16(a, b, acc[ct], 0, 0, 0);
        }
        __syncthreads();
    }

    // D mapping: col = ct*16 + (lane&15), row = w*16 + (lane>>4)*4 + r
    #pragma unroll
    for (int ct = 0; ct < 4; ++ct) {
        #pragma unroll
        for (int r = 0; r < 4; ++r) {
            int grow = rowBase + w * 16 + kg * 4 + r;
            if (grow < M) H[(size_t)grow * HID + ct * 16 + l15] = __float2half(acc[ct][r]);
        }
    }
}

// ---------- agg pass 1: z = relu(A*h + b1), fp16 in/out, one wave per node ----------
__global__ __launch_bounds__(256) void agg_relu_kernel(const __half* __restrict__ h,
                                                       const int* __restrict__ off,
                                                       const int* __restrict__ csr_src,
                                                       const float* __restrict__ dinv,
                                                       const float* __restrict__ b1,
                                                       __half* __restrict__ z, int M) {
    const int lane = threadIdx.x & 63;
    const int n = blockIdx.x * 4 + (threadIdx.x >> 6);
    if (n >= M) return;

    const float di = dinv[n];
    float acc = __half2float(h[(size_t)n * HID + lane]) * di * di;   // self-loop

    const int s0 = off[n], s1 = off[n + 1];
    for (int e = s0; e < s1; ) {
        int   s  = 0;
        float nm = 0.f;
        if (e + lane < s1) {
            s  = csr_src[e + lane];
            nm = dinv[s] * di;
        }
        const int cnt = min(64, s1 - e);
        int j = 0;
        for (; j + 4 <= cnt; j += 4) {
            int sa = __shfl(s, j);
            int sb = __shfl(s, j + 1);
            int sc = __shfl(s, j + 2);
            int sd = __shfl(s, j + 3);
            float na = __shfl(nm, j);
            float nb = __shfl(nm, j + 1);
            float nc = __shfl(nm, j + 2);
            float nd = __shfl(nm, j + 3);
            float va = __half2float(h[(size_t)sa * HID + lane]);
            float vb = __half2float(h[(size_t)sb * HID + lane]);
            float vc = __half2float(h[(size_t)sc * HID + lane]);
            float vd = __half2float(h[(size_t)sd * HID + lane]);
            acc = fmaf(va, na, acc);
            acc = fmaf(vb, nb, acc);
            acc = fmaf(vc, nc, acc);
            acc = fmaf(vd, nd, acc);
        }
        for (; j < cnt; ++j) {
            int sj = __shfl(s, j);
            float nj = __shfl(nm, j);
            acc = fmaf(__half2float(h[(size_t)sj * HID + lane]), nj, acc);
        }
        e += cnt;
    }

    acc = fmaxf(acc + b1[lane], 0.0f);
    z[(size_t)n * HID + lane] = __float2half(acc);
}

// ---------- GEMM2: h2 = z (Mx64, fp16) @ W2 (64x40) -> fp16, no bias ----------
__global__ __launch_bounds__(256) void gemm2_kernel(const __half* __restrict__ z,
                                                    const float* __restrict__ W2,
                                                    __half* __restrict__ h2, int M) {
    __shared__ float W2s[HID * NCLS];   // 10.24 KB
    __shared__ float zs[64 * HID];      // 16 KB

    const int tid = threadIdx.x;
    const int rowBase = blockIdx.x * 64;

    for (int i = tid; i < HID * NCLS; i += 256) W2s[i] = W2[i];

    #pragma unroll
    for (int p = 0; p < 2; ++p) {
        int o = tid * 2 + p;            // 0..511 chunks of 8 halves
        int r = o >> 3, c8 = o & 7;
        int gr = rowBase + r;
        float4 raw = make_float4(0.f, 0.f, 0.f, 0.f);
        if (gr < M) raw = *reinterpret_cast<const float4*>(&z[(size_t)gr * HID + c8 * 8]);
        const __half2* hp = reinterpret_cast<const __half2*>(&raw);
        #pragma unroll
        for (int q = 0; q < 4; ++q) {
            float2 f = __half22float2(hp[q]);
            zs[r * HID + c8 * 8 + q * 2]     = f.x;
            zs[r * HID + c8 * 8 + q * 2 + 1] = f.y;
        }
    }
    __syncthreads();

    #pragma unroll
    for (int p = 0; p < 10; ++p) {
        int o = p * 256 + tid;          // 0..2559 = 64 rows x 40 cols
        int r = o / NCLS, j = o - r * NCLS;
        float s = 0.f;
        #pragma unroll
        for (int k = 0; k < HID; ++k) s = fmaf(zs[r * HID + k], W2s[k * NCLS + j], s);
        int gr = rowBase + r;
        if (gr < M) h2[(size_t)gr * NCLS + j] = __float2half(s);
    }
}

// ---------- agg pass 2: out = log_softmax(A*h2 + b2), 40-wide, one wave per node ----------
__global__ __launch_bounds__(256) void agg2_lsm_kernel(const __half* __restrict__ h2,
                                                       const int* __restrict__ off,
                                                       const int* __restrict__ csr_src,
                                                       const float* __restrict__ dinv,
                                                       const float* __restrict__ b2,
                                                       float* __restrict__ out, int M) {
    const int lane = threadIdx.x & 63;
    const int n = blockIdx.x * 4 + (threadIdx.x >> 6);
    if (n >= M) return;

    const float di = dinv[n];
    float acc = 0.f;
    if (lane < NCLS) acc = __half2float(h2[(size_t)n * NCLS + lane]) * di * di;  // self-loop

    const int s0 = off[n], s1 = off[n + 1];
    for (int e = s0; e < s1; ) {
        int   s  = 0;
        float nm = 0.f;
        if (e + lane < s1) {
            s  = csr_src[e + lane];
            nm = dinv[s] * di;
        }
        const int cnt = min(64, s1 - e);
        int j = 0;
        for (; j + 4 <= cnt; j += 4) {
            int sa = __shfl(s, j);
            int sb = __shfl(s, j + 1);
            int sc = __shfl(s, j + 2);
            int sd = __shfl(s, j + 3);
            float na = __shfl(nm, j);
            float nb = __shfl(nm, j + 1);
            float nc = __shfl(nm, j + 2);
            float nd = __shfl(nm, j + 3);
            if (lane < NCLS) {
                float va = __half2float(h2[(size_t)sa * NCLS + lane]);
                float vb = __half2float(h2[(size_t)sb * NCLS + lane]);
                float vc = __half2float(h2[(size_t)sc * NCLS + lane]);
                float vd = __half2float(h2[(size_t)sd * NCLS + lane]);
                acc = fmaf(va, na, acc);
                acc = fmaf(vb, nb, acc);
                acc = fmaf(vc, nc, acc);
                acc = fmaf(vd, nd, acc);
            }
        }
        for (; j < cnt; ++j) {
            int sj = __shfl(s, j);
            float nj = __shfl(nm, j);
            if (lane < NCLS) acc = fmaf(__half2float(h2[(size_t)sj * NCLS + lane]), nj, acc);
        }
        e += cnt;
    }

    // bias + wave-wide log_softmax over lanes 0..39
    float logit = (lane < NCLS) ? (acc + b2[lane]) : -1e30f;
    float m = logit;
    #pragma unroll
    for (int o = 32; o >= 1; o >>= 1) m = fmaxf(m, __shfl_xor(m, o));
    float ex = (lane < NCLS) ? expf(logit - m) : 0.f;
    float sm = ex;
    #pragma unroll
    for (int o = 32; o >= 1; o >>= 1) sm += __shfl_xor(sm, o);
    float res = logit - m - logf(sm);

    if (lane < NCLS) out[(size_t)n * NCLS + lane] = res;
}

extern "C" void kernel_launch(void* const* d_in, const int* in_sizes, int n_in,
                              void* d_out, int out_size, void* d_ws, size_t ws_size,
                              hipStream_t stream) {
    const float* x  = (const float*)d_in[0];
    const int*   ei = (const int*)d_in[1];
    const float* W1 = (const float*)d_in[2];
    const float* b1 = (const float*)d_in[3];
    const float* W2 = (const float*)d_in[4];
    const float* b2 = (const float*)d_in[5];
    float* out = (float*)d_out;

    const int M = N_NODES;
    const int E = in_sizes[1] / 2;
    const int* src = ei;
    const int* dst = ei + E;

    // ---- workspace layout (peak ~48.4 MB; ws_size ≈ 800 MB per fill counters) ----
    char* ws = (char*)d_ws;
    int*          cnt     = (int*)         (ws + 0);           // 400 KB
    float*        dinv    = (float*)       (ws + 409600);      // 400 KB
    int*          off     = (int*)         (ws + 819200);      // 400 KB + 4
    int*          part    = (int*)         (ws + 1232896);     // 392 B
    int*          bcur    = (int*)         (ws + 1236992);     // 12500*64 B = 800 KB
    int*          csr_src = (int*)         (ws + 2036992);     // 6.4 MB
    unsigned int* ebuf    = (unsigned int*)(ws + 8436992);     // 6.4 MB
    __half*       h1      = (__half*)      (ws + 14836992);    // 12.8 MB
    __half*       z       = (__half*)      (ws + 27636992);    // 12.8 MB
    __half*       h2      = (__half*)      (ws + 40436992);    // 8 MB -> ends 48,436,992

    const int nPart = (M + SCAN_ELEMS - 1) / SCAN_ELEMS;  // 98

    zero_kernel<<<(M + 255) / 256, 256, 0, stream>>>(cnt, M);
    count_deg_kernel<<<(E + 255) / 256, 256, 0, stream>>>(dst, cnt, E);

    scan_partial_kernel<<<nPart, 256, 0, stream>>>(cnt, part, M);
    scan_single_kernel<<<1, 128, 0, stream>>>(part, nPart);
    scan_final_kernel<<<nPart, 256, 0, stream>>>(cnt, part, off, dinv, bcur, M);

    scatter_bucket_kernel<<<(E + 255) / 256, 256, 0, stream>>>(src, dst, bcur, ebuf, E);
    sort_bucket_kernel<<<NBUCK, 64, 0, stream>>>(ebuf, off, csr_src, M);

    gemm1_mfma_kernel<<<(M + 63) / 64, 256, 0, stream>>>(x, W1, h1, M);

    agg_relu_kernel<<<(M + 3) / 4, 256, 0, stream>>>(h1, off, csr_src, dinv, b1, z, M);

    gemm2_kernel<<<(M + 63) / 64, 256, 0, stream>>>(z, W2, h2, M);
    agg2_lsm_kernel<<<(M + 3) / 4, 256, 0, stream>>>(h2, off, csr_src, dinv, b2, out, M);
}

// Round 11
// 369.887 us; speedup vs baseline: 1.2757x; 1.1174x over previous
//
#include <hip/hip_runtime.h>
#include <hip/hip_bf16.h>
#include <hip/hip_fp16.h>
#include <cstddef>

#define N_NODES 100000
#define F_IN    512
#define HID     64
#define NCLS    40

#define BUCK_SZ   8
#define NBUCK     (N_NODES / BUCK_SZ)     // 12500, exact
#define SRC_MASK  0x1FFFF                  // 17 bits
#define CUR_PAD   16                       // ints: one cursor per 64B line

#define NPART      8
#define PART_NODES 12512                   // ceil(100000/8) rounded to BUCK_SZ multiple
#define PART_BLOCKS 256                    // blocks per partition

using half8 = __attribute__((ext_vector_type(8))) _Float16;
using f32x4 = __attribute__((ext_vector_type(4))) float;

// ---------- utility ----------
__global__ void zero_kernel(int* __restrict__ p, int n) {
    int i = blockIdx.x * blockDim.x + threadIdx.x;
    if (i < n) p[i] = 0;
}

// ---------- degree count, XCD-partitioned ----------
// partition p = blockIdx & 7 -> lands on XCD p (round-robin dispatch);
// each partition scans the full dst list, counts only its node range ->
// cnt lines stay in one XCD's L2 (no cross-XCD atomic ping-pong).
__global__ __launch_bounds__(256) void count_part_kernel(const int* __restrict__ dst,
                                                         int* __restrict__ cnt, int E) {
    const int p  = blockIdx.x & (NPART - 1);
    const int bi = blockIdx.x >> 3;
    const int nb = gridDim.x >> 3;
    const int lo = p * PART_NODES, hi = lo + PART_NODES;
    for (int e = bi * 256 + (int)threadIdx.x; e < E; e += nb * 256) {
        int d = dst[e];
        if (d >= lo && d < hi) atomicAdd(&cnt[d], 1);
    }
}

// ---------- exclusive scan (2-level) over degree counts ----------
#define SCAN_ELEMS 1024

__global__ __launch_bounds__(256) void scan_partial_kernel(const int* __restrict__ cnt,
                                                           int* __restrict__ part, int M) {
    __shared__ int sd[256];
    const int b = blockIdx.x, t = threadIdx.x;
    const int base = b * SCAN_ELEMS;
    int s = 0;
    for (int i = t; i < SCAN_ELEMS; i += 256) {
        int idx = base + i;
        s += (idx < M) ? cnt[idx] : 0;
    }
    sd[t] = s; __syncthreads();
    for (int d = 128; d > 0; d >>= 1) {
        if (t < d) sd[t] += sd[t + d];
        __syncthreads();
    }
    if (t == 0) part[b] = sd[0];
}

__global__ void scan_single_kernel(int* __restrict__ part, int n) {
    __shared__ int sd[128];
    int t = threadIdx.x;
    int v = (t < n) ? part[t] : 0;
    sd[t] = v; __syncthreads();
    for (int d = 1; d < 128; d <<= 1) {
        int u = (t >= d) ? sd[t - d] : 0;
        __syncthreads();
        sd[t] += u;
        __syncthreads();
    }
    if (t < n) part[t] = sd[t] - v;   // exclusive
}

// scan_final also emits dinv and bucket cursors
__global__ __launch_bounds__(256) void scan_final_kernel(const int* __restrict__ cnt,
                                                         const int* __restrict__ part,
                                                         int* __restrict__ off,
                                                         float* __restrict__ dinv,
                                                         int* __restrict__ bcur, int M) {
    __shared__ int sd[256];
    const int b = blockIdx.x, t = threadIdx.x;
    const int base = b * SCAN_ELEMS + t * 4;
    int cs[4];
    #pragma unroll
    for (int i = 0; i < 4; ++i) cs[i] = (base + i < M) ? cnt[base + i] : 0;
    const int tot = cs[0] + cs[1] + cs[2] + cs[3];
    sd[t] = tot; __syncthreads();
    for (int d = 1; d < 256; d <<= 1) {
        int u = (t >= d) ? sd[t - d] : 0;
        __syncthreads();
        sd[t] += u;
        __syncthreads();
    }
    int run = sd[t] - tot + part[b];
    #pragma unroll
    for (int i = 0; i < 4; ++i) {
        int node = base + i;
        if (node < M) {
            off[node] = run;
            dinv[node] = rsqrtf((float)(cs[i] + 1));          // +1 self-loop
            if ((node & (BUCK_SZ - 1)) == 0)
                bcur[(node / BUCK_SZ) * CUR_PAD] = run;       // bucket cursor start
        }
        run += cs[i];
    }
    if (base < M && base + 4 >= M) off[M] = run;
}

// ---------- phase 1: XCD-partitioned scatter into dst-buckets ----------
// same partition trick: all writers of a bucket window share an XCD, so
// ebuf lines fill in-cache (16 x 4B appends) instead of bouncing.
__global__ __launch_bounds__(256) void scatter_part_kernel(const int* __restrict__ src,
                                                           const int* __restrict__ dst,
                                                           int* __restrict__ bcur,
                                                           unsigned int* __restrict__ ebuf,
                                                           int E) {
    const int p  = blockIdx.x & (NPART - 1);
    const int bi = blockIdx.x >> 3;
    const int nb = gridDim.x >> 3;
    const int lo = p * PART_NODES, hi = lo + PART_NODES;
    for (int e = bi * 256 + (int)threadIdx.x; e < E; e += nb * 256) {
        int d = dst[e];
        if (d >= lo && d < hi) {
            int s = src[e];
            int b = d >> 3;   // BUCK_SZ = 8
            int pos = atomicAdd(&bcur[b * CUR_PAD], 1);
            ebuf[pos] = (unsigned int)s | ((unsigned int)(d & (BUCK_SZ - 1)) << 17);
        }
    }
}

// ---------- phase 2: within-bucket counting place -> per-node CSR ----------
__global__ __launch_bounds__(64) void sort_bucket_kernel(const unsigned int* __restrict__ ebuf,
                                                         const int* __restrict__ off,
                                                         int* __restrict__ csr_src, int M) {
    __shared__ int lcur[BUCK_SZ];
    const int b = blockIdx.x, t = threadIdx.x;
    const int base = b * BUCK_SZ;
    if (t < BUCK_SZ) lcur[t] = off[base + t];
    __syncthreads();
    const int e0 = off[base];
    const int e1 = off[base + BUCK_SZ];
    for (int e = e0 + t; e < e1; e += 64) {
        unsigned int pk = ebuf[e];
        int loc = pk >> 17;
        int pos = atomicAdd(&lcur[loc], 1);
        csr_src[pos] = (int)(pk & SRC_MASK);
    }
}

// ---------- GEMM1 (MFMA fp16): H1 = X (Mx512) @ W1 (512x64), fp16 out ----------
__global__ __launch_bounds__(256) void gemm1_mfma_kernel(const float* __restrict__ X,
                                                         const float* __restrict__ W,
                                                         __half* __restrict__ H, int M) {
    __shared__ _Float16 As[4][64][8];   // 4 KB
    __shared__ _Float16 Bs[4][64][8];   // 4 KB

    const int tid  = threadIdx.x;
    const int lane = tid & 63;
    const int w    = tid >> 6;
    const int l15  = lane & 15;
    const int kg   = lane >> 4;
    const int rowBase = blockIdx.x * 64;

    f32x4 acc[4] = {};

    for (int kt = 0; kt < F_IN; kt += 32) {
        #pragma unroll
        for (int p = 0; p < 2; ++p) {
            int idx = tid * 2 + p;           // 0..511
            int r = idx >> 3, k4 = idx & 7;  // row, k-quad
            int gr = rowBase + r; if (gr >= M) gr = M - 1;
            const float4 v = *reinterpret_cast<const float4*>(
                &X[(size_t)gr * F_IN + kt + k4 * 4]);
            _Float16* dstp = &As[k4 >> 1][r][(k4 & 1) * 4];
            dstp[0] = (_Float16)v.x; dstp[1] = (_Float16)v.y;
            dstp[2] = (_Float16)v.z; dstp[3] = (_Float16)v.w;
        }
        #pragma unroll
        for (int p = 0; p < 2; ++p) {
            int idx = tid * 2 + p;           // 0..511
            int k = idx >> 4, c4 = idx & 15;
            const float4 v = *reinterpret_cast<const float4*>(
                &W[(size_t)(kt + k) * HID + c4 * 4]);
            int kgg = k >> 3, j = k & 7;
            Bs[kgg][c4 * 4 + 0][j] = (_Float16)v.x;
            Bs[kgg][c4 * 4 + 1][j] = (_Float16)v.y;
            Bs[kgg][c4 * 4 + 2][j] = (_Float16)v.z;
            Bs[kgg][c4 * 4 + 3][j] = (_Float16)v.w;
        }
        __syncthreads();

        const half8 a = *reinterpret_cast<const half8*>(&As[kg][w * 16 + l15][0]);
        #pragma unroll
        for (int ct = 0; ct < 4; ++ct) {
            const half8 b = *reinterpret_cast<const half8*>(&Bs[kg][ct * 16 + l15][0]);
            acc[ct] = __builtin_amdgcn_mfma_f32_16x16x32_f16(a, b, acc[ct], 0, 0, 0);
        }
        __syncthreads();
    }

    #pragma unroll
    for (int ct = 0; ct < 4; ++ct) {
        #pragma unroll
        for (int r = 0; r < 4; ++r) {
            int grow = rowBase + w * 16 + kg * 4 + r;
            if (grow < M) H[(size_t)grow * HID + ct * 16 + l15] = __float2half(acc[ct][r]);
        }
    }
}

// ---------- agg pass 1: z = relu(A*h + b1), fp16 in/out, one wave per node ----------
__global__ __launch_bounds__(256) void agg_relu_kernel(const __half* __restrict__ h,
                                                       const int* __restrict__ off,
                                                       const int* __restrict__ csr_src,
                                                       const float* __restrict__ dinv,
                                                       const float* __restrict__ b1,
                                                       __half* __restrict__ z, int M) {
    const int lane = threadIdx.x & 63;
    const int n = blockIdx.x * 4 + (threadIdx.x >> 6);
    if (n >= M) return;

    const float di = dinv[n];
    float acc = __half2float(h[(size_t)n * HID + lane]) * di * di;   // self-loop

    const int s0 = off[n], s1 = off[n + 1];
    for (int e = s0; e < s1; ) {
        int   s  = 0;
        float nm = 0.f;
        if (e + lane < s1) {
            s  = csr_src[e + lane];
            nm = dinv[s] * di;
        }
        const int cnt = min(64, s1 - e);
        int j = 0;
        for (; j + 4 <= cnt; j += 4) {
            int sa = __shfl(s, j);
            int sb = __shfl(s, j + 1);
            int sc = __shfl(s, j + 2);
            int sd = __shfl(s, j + 3);
            float na = __shfl(nm, j);
            float nb = __shfl(nm, j + 1);
            float nc = __shfl(nm, j + 2);
            float nd = __shfl(nm, j + 3);
            float va = __half2float(h[(size_t)sa * HID + lane]);
            float vb = __half2float(h[(size_t)sb * HID + lane]);
            float vc = __half2float(h[(size_t)sc * HID + lane]);
            float vd = __half2float(h[(size_t)sd * HID + lane]);
            acc = fmaf(va, na, acc);
            acc = fmaf(vb, nb, acc);
            acc = fmaf(vc, nc, acc);
            acc = fmaf(vd, nd, acc);
        }
        for (; j < cnt; ++j) {
            int sj = __shfl(s, j);
            float nj = __shfl(nm, j);
            acc = fmaf(__half2float(h[(size_t)sj * HID + lane]), nj, acc);
        }
        e += cnt;
    }

    acc = fmaxf(acc + b1[lane], 0.0f);
    z[(size_t)n * HID + lane] = __float2half(acc);
}

// ---------- GEMM2: h2 = z (Mx64, fp16) @ W2 (64x40) -> fp16, no bias ----------
__global__ __launch_bounds__(256) void gemm2_kernel(const __half* __restrict__ z,
                                                    const float* __restrict__ W2,
                                                    __half* __restrict__ h2, int M) {
    __shared__ float W2s[HID * NCLS];   // 10.24 KB
    __shared__ float zs[64 * HID];      // 16 KB

    const int tid = threadIdx.x;
    const int rowBase = blockIdx.x * 64;

    for (int i = tid; i < HID * NCLS; i += 256) W2s[i] = W2[i];

    #pragma unroll
    for (int p = 0; p < 2; ++p) {
        int o = tid * 2 + p;            // 0..511 chunks of 8 halves
        int r = o >> 3, c8 = o & 7;
        int gr = rowBase + r;
        float4 raw = make_float4(0.f, 0.f, 0.f, 0.f);
        if (gr < M) raw = *reinterpret_cast<const float4*>(&z[(size_t)gr * HID + c8 * 8]);
        const __half2* hp = reinterpret_cast<const __half2*>(&raw);
        #pragma unroll
        for (int q = 0; q < 4; ++q) {
            float2 f = __half22float2(hp[q]);
            zs[r * HID + c8 * 8 + q * 2]     = f.x;
            zs[r * HID + c8 * 8 + q * 2 + 1] = f.y;
        }
    }
    __syncthreads();

    #pragma unroll
    for (int p = 0; p < 10; ++p) {
        int o = p * 256 + tid;          // 0..2559 = 64 rows x 40 cols
        int r = o / NCLS, j = o - r * NCLS;
        float s = 0.f;
        #pragma unroll
        for (int k = 0; k < HID; ++k) s = fmaf(zs[r * HID + k], W2s[k * NCLS + j], s);
        int gr = rowBase + r;
        if (gr < M) h2[(size_t)gr * NCLS + j] = __float2half(s);
    }
}

// ---------- agg pass 2: out = log_softmax(A*h2 + b2), 40-wide, one wave per node ----------
__global__ __launch_bounds__(256) void agg2_lsm_kernel(const __half* __restrict__ h2,
                                                       const int* __restrict__ off,
                                                       const int* __restrict__ csr_src,
                                                       const float* __restrict__ dinv,
                                                       const float* __restrict__ b2,
                                                       float* __restrict__ out, int M) {
    const int lane = threadIdx.x & 63;
    const int n = blockIdx.x * 4 + (threadIdx.x >> 6);
    if (n >= M) return;

    const float di = dinv[n];
    float acc = 0.f;
    if (lane < NCLS) acc = __half2float(h2[(size_t)n * NCLS + lane]) * di * di;  // self-loop

    const int s0 = off[n], s1 = off[n + 1];
    for (int e = s0; e < s1; ) {
        int   s  = 0;
        float nm = 0.f;
        if (e + lane < s1) {
            s  = csr_src[e + lane];
            nm = dinv[s] * di;
        }
        const int cnt = min(64, s1 - e);
        int j = 0;
        for (; j + 4 <= cnt; j += 4) {
            int sa = __shfl(s, j);
            int sb = __shfl(s, j + 1);
            int sc = __shfl(s, j + 2);
            int sd = __shfl(s, j + 3);
            float na = __shfl(nm, j);
            float nb = __shfl(nm, j + 1);
            float nc = __shfl(nm, j + 2);
            float nd = __shfl(nm, j + 3);
            if (lane < NCLS) {
                float va = __half2float(h2[(size_t)sa * NCLS + lane]);
                float vb = __half2float(h2[(size_t)sb * NCLS + lane]);
                float vc = __half2float(h2[(size_t)sc * NCLS + lane]);
                float vd = __half2float(h2[(size_t)sd * NCLS + lane]);
                acc = fmaf(va, na, acc);
                acc = fmaf(vb, nb, acc);
                acc = fmaf(vc, nc, acc);
                acc = fmaf(vd, nd, acc);
            }
        }
        for (; j < cnt; ++j) {
            int sj = __shfl(s, j);
            float nj = __shfl(nm, j);
            if (lane < NCLS) acc = fmaf(__half2float(h2[(size_t)sj * NCLS + lane]), nj, acc);
        }
        e += cnt;
    }

    float logit = (lane < NCLS) ? (acc + b2[lane]) : -1e30f;
    float m = logit;
    #pragma unroll
    for (int o = 32; o >= 1; o >>= 1) m = fmaxf(m, __shfl_xor(m, o));
    float ex = (lane < NCLS) ? expf(logit - m) : 0.f;
    float sm = ex;
    #pragma unroll
    for (int o = 32; o >= 1; o >>= 1) sm += __shfl_xor(sm, o);
    float res = logit - m - logf(sm);

    if (lane < NCLS) out[(size_t)n * NCLS + lane] = res;
}

extern "C" void kernel_launch(void* const* d_in, const int* in_sizes, int n_in,
                              void* d_out, int out_size, void* d_ws, size_t ws_size,
                              hipStream_t stream) {
    const float* x  = (const float*)d_in[0];
    const int*   ei = (const int*)d_in[1];
    const float* W1 = (const float*)d_in[2];
    const float* b1 = (const float*)d_in[3];
    const float* W2 = (const float*)d_in[4];
    const float* b2 = (const float*)d_in[5];
    float* out = (float*)d_out;

    const int M = N_NODES;
    const int E = in_sizes[1] / 2;
    const int* src = ei;
    const int* dst = ei + E;

    // ---- workspace layout (peak ~48.4 MB; ws_size ≈ 800 MB per fill counters) ----
    char* ws = (char*)d_ws;
    int*          cnt     = (int*)         (ws + 0);           // 400 KB
    float*        dinv    = (float*)       (ws + 409600);      // 400 KB
    int*          off     = (int*)         (ws + 819200);      // 400 KB + 4
    int*          part    = (int*)         (ws + 1232896);     // 392 B
    int*          bcur    = (int*)         (ws + 1236992);     // 12500*64 B = 800 KB
    int*          csr_src = (int*)         (ws + 2036992);     // 6.4 MB
    unsigned int* ebuf    = (unsigned int*)(ws + 8436992);     // 6.4 MB
    __half*       h1      = (__half*)      (ws + 14836992);    // 12.8 MB
    __half*       z       = (__half*)      (ws + 27636992);    // 12.8 MB
    __half*       h2      = (__half*)      (ws + 40436992);    // 8 MB -> ends 48,436,992

    const int nPart = (M + SCAN_ELEMS - 1) / SCAN_ELEMS;  // 98

    zero_kernel<<<(M + 255) / 256, 256, 0, stream>>>(cnt, M);
    count_part_kernel<<<NPART * PART_BLOCKS, 256, 0, stream>>>(dst, cnt, E);

    scan_partial_kernel<<<nPart, 256, 0, stream>>>(cnt, part, M);
    scan_single_kernel<<<1, 128, 0, stream>>>(part, nPart);
    scan_final_kernel<<<nPart, 256, 0, stream>>>(cnt, part, off, dinv, bcur, M);

    scatter_part_kernel<<<NPART * PART_BLOCKS, 256, 0, stream>>>(src, dst, bcur, ebuf, E);
    sort_bucket_kernel<<<NBUCK, 64, 0, stream>>>(ebuf, off, csr_src, M);

    gemm1_mfma_kernel<<<(M + 63) / 64, 256, 0, stream>>>(x, W1, h1, M);

    agg_relu_kernel<<<(M + 3) / 4, 256, 0, stream>>>(h1, off, csr_src, dinv, b1, z, M);

    gemm2_kernel<<<(M + 63) / 64, 256, 0, stream>>>(z, W2, h2, M);
    agg2_lsm_kernel<<<(M + 3) / 4, 256, 0, stream>>>(h2, off, csr_src, dinv, b2, out, M);
}